// Round 1
// baseline (4517.056 us; speedup 1.0000x reference)
//
#include <hip/hip_runtime.h>

// Problem constants
// B=32, C_IN=64, C_OUT=64, N=1024, T=16
// x:[B,64,1024,16] adj:[1024,1024] alpha:[64] W_att:[16,16] W_out:[64,64]
// out:[B,64,1024,16]
//
// Decomposition:
//  kA: k[b,n,t]  = sum_i x[b,i,n,t]*alpha[i];  kq[b,n,s] = sum_t k[b,n,t]*W_att[t,s]
//  kB: rowmax[b,n] = max_m score(b,n,m); rrsum = 1/sum_m exp(score-max)
//      where score(b,n,m) = sum_s kq[b,n,s]*k[b,m,s]
//  kC: y[b,o,m,t] = sum_c W_out[o,c]*x[b,c,m,t]
//  kD: out[b,o,n,t] = sum_m [exp(score-max)*rrsum*adj[n,m]] * y[b,o,m,t]
//      (att recomputed on the fly; scores/att never materialized)

__global__ __launch_bounds__(256) void kA(const float* __restrict__ x,
                                          const float* __restrict__ alpha,
                                          const float* __restrict__ Watt,
                                          float* __restrict__ kk_,
                                          float* __restrict__ kq_) {
    __shared__ float al[64];
    __shared__ float kl[16][17];
    __shared__ float wl[16][16];
    int tid = threadIdx.x;
    if (tid < 64) al[tid] = alpha[tid];
    int rl = tid >> 4, t = tid & 15;
    wl[rl][t] = Watt[tid];               // wl[t_row][s]
    __syncthreads();
    size_t row = (size_t)blockIdx.x * 16 + rl;   // b*1024 + n
    int b = (int)(row >> 10);
    int n = (int)(row & 1023);
    const float* xp = x + (size_t)b * (64 * 16384) + (size_t)n * 16 + t;
    float acc = 0.f;
    #pragma unroll
    for (int i = 0; i < 64; ++i) acc = fmaf(xp[(size_t)i * 16384], al[i], acc);
    kl[rl][t] = acc;
    __syncthreads();
    float q = 0.f;
    #pragma unroll
    for (int s = 0; s < 16; ++s) q = fmaf(kl[rl][s], wl[s][t], q);
    kk_[row * 16 + t] = acc;
    kq_[row * 16 + t] = q;
}

__global__ __launch_bounds__(256) void kB(const float* __restrict__ kk_,
                                          const float* __restrict__ kq_,
                                          float* __restrict__ rmax,
                                          float* __restrict__ rrsum) {
    size_t row = blockIdx.x;             // b*1024 + n
    int b = (int)(row >> 10);
    int tid = threadIdx.x;
    __shared__ float kql[16];
    if (tid < 16) kql[tid] = kq_[row * 16 + tid];
    __syncthreads();
    const float* kb = kk_ + (size_t)b * 16384;
    float s[4];
    #pragma unroll
    for (int u = 0; u < 4; ++u) {
        int m = tid + u * 256;
        const float* kp = kb + (size_t)m * 16;
        float acc = 0.f;
        #pragma unroll
        for (int t = 0; t < 16; ++t) acc = fmaf(kql[t], kp[t], acc);
        s[u] = acc;
    }
    float mx = fmaxf(fmaxf(s[0], s[1]), fmaxf(s[2], s[3]));
    #pragma unroll
    for (int off = 32; off; off >>= 1) mx = fmaxf(mx, __shfl_xor(mx, off));
    __shared__ float red[4], red2[4];
    if ((tid & 63) == 0) red[tid >> 6] = mx;
    __syncthreads();
    mx = fmaxf(fmaxf(red[0], red[1]), fmaxf(red[2], red[3]));
    float se = 0.f;
    #pragma unroll
    for (int u = 0; u < 4; ++u) se += __expf(s[u] - mx);
    #pragma unroll
    for (int off = 32; off; off >>= 1) se += __shfl_xor(se, off);
    if ((tid & 63) == 0) red2[tid >> 6] = se;
    __syncthreads();
    se = red2[0] + red2[1] + red2[2] + red2[3];
    if (tid == 0) { rmax[row] = mx; rrsum[row] = 1.f / se; }
}

__global__ __launch_bounds__(256) void kC(const float* __restrict__ x,
                                          const float* __restrict__ Wout,
                                          float* __restrict__ y) {
    __shared__ __align__(16) float Xt[64][68];
    __shared__ __align__(16) float WT[64][68];   // WT[c][o]
    int tid = threadIdx.x;
    int b = blockIdx.x >> 8;
    int j0 = (blockIdx.x & 255) * 64;            // j = m*16+t flat over 16384
    #pragma unroll
    for (int it = 0; it < 16; ++it) {
        int idx = it * 256 + tid;
        int o = idx >> 6, c = idx & 63;
        WT[c][o] = Wout[idx];
        int c2 = it * 4 + (tid >> 6), j = tid & 63;
        Xt[c2][j] = x[(size_t)(b * 64 + c2) * 16384 + j0 + j];
    }
    __syncthreads();
    int oy = tid >> 4, jx = tid & 15;
    float acc[4][4] = {};
    #pragma unroll
    for (int c = 0; c < 64; ++c) {
        float4 w4 = *(const float4*)&WT[c][oy * 4];
        float4 x4 = *(const float4*)&Xt[c][jx * 4];
        float wv[4] = {w4.x, w4.y, w4.z, w4.w};
        float xv[4] = {x4.x, x4.y, x4.z, x4.w};
        #pragma unroll
        for (int u = 0; u < 4; ++u)
            #pragma unroll
            for (int v = 0; v < 4; ++v)
                acc[u][v] = fmaf(wv[u], xv[v], acc[u][v]);
    }
    #pragma unroll
    for (int u = 0; u < 4; ++u) {
        int o = oy * 4 + u;
        *(float4*)&y[(size_t)(b * 64 + o) * 16384 + j0 + jx * 4] =
            make_float4(acc[u][0], acc[u][1], acc[u][2], acc[u][3]);
    }
}

// Tile: 64 n-rows x 256 cols (16 o * 16 t), K-chunk 32 m. 256 thr, 8x8 micro.
__global__ __launch_bounds__(256) void kD(const float* __restrict__ kk_,
                                          const float* __restrict__ kq_,
                                          const float* __restrict__ rmax,
                                          const float* __restrict__ rrsum,
                                          const float* __restrict__ adj,
                                          const float* __restrict__ y,
                                          float* __restrict__ out) {
    __shared__ __align__(16) float Pl[64][33];
    __shared__ __align__(16) float Yt[32][260];
    __shared__ float kql[64][17];
    __shared__ float mxl[64], rsl[64];
    int tid = threadIdx.x;
    int n0 = blockIdx.x * 64;
    int o0 = blockIdx.y * 16;
    int b  = blockIdx.z;
    #pragma unroll
    for (int it = 0; it < 4; ++it) {
        int idx = it * 256 + tid;
        int rr = idx >> 4, s = idx & 15;
        kql[rr][s] = kq_[((size_t)b * 1024 + n0 + rr) * 16 + s];
    }
    if (tid < 64) {
        mxl[tid] = rmax[(size_t)b * 1024 + n0 + tid];
        rsl[tid] = rrsum[(size_t)b * 1024 + n0 + tid];
    }
    __syncthreads();
    const float* kb = kk_ + (size_t)b * 16384;
    const float* ybase = y + (size_t)b * 64 * 16384;
    int ny = tid >> 5, cx = tid & 31;
    float acc[8][8] = {};
    for (int mc = 0; mc < 32; ++mc) {
        int m0 = mc * 32;
        // stage P = softmax(score)*adj  (recomputed from kq.k, identical fma order to kB)
        #pragma unroll
        for (int it = 0; it < 8; ++it) {
            int e = it * 256 + tid;
            int pn = e >> 5, pm = e & 31;
            const float* kp = kb + (size_t)(m0 + pm) * 16;
            float sc = 0.f;
            #pragma unroll
            for (int s = 0; s < 16; ++s) sc = fmaf(kql[pn][s], kp[s], sc);
            Pl[pn][pm] = __expf(sc - mxl[pn]) * rsl[pn] *
                         adj[(size_t)(n0 + pn) * 1024 + m0 + pm];
        }
        // stage Y chunk [32 m][16 o * 16 t]
        #pragma unroll
        for (int it = 0; it < 32; ++it) {
            int idx = it * 256 + tid;
            int oo = idx >> 9, w = idx & 511;
            int mm = w >> 4, t = w & 15;
            Yt[mm][oo * 16 + t] =
                ybase[(size_t)(o0 + oo) * 16384 + (size_t)(m0 + mm) * 16 + t];
        }
        __syncthreads();
        #pragma unroll 2
        for (int kx = 0; kx < 32; ++kx) {
            float pv[8];
            #pragma unroll
            for (int r = 0; r < 8; ++r) pv[r] = Pl[ny * 8 + r][kx];
            float4 ya = *(const float4*)&Yt[kx][cx * 8];
            float4 yb4 = *(const float4*)&Yt[kx][cx * 8 + 4];
            float yv[8] = {ya.x, ya.y, ya.z, ya.w, yb4.x, yb4.y, yb4.z, yb4.w};
            #pragma unroll
            for (int r = 0; r < 8; ++r)
                #pragma unroll
                for (int v = 0; v < 8; ++v)
                    acc[r][v] = fmaf(pv[r], yv[v], acc[r][v]);
        }
        __syncthreads();
    }
    int oo = cx >> 1, t0 = (cx & 1) * 8;
    #pragma unroll
    for (int r = 0; r < 8; ++r) {
        int n = n0 + ny * 8 + r;
        float* op = out + ((size_t)b * 64 + o0 + oo) * 16384 + (size_t)n * 16 + t0;
        *(float4*)&op[0] = make_float4(acc[r][0], acc[r][1], acc[r][2], acc[r][3]);
        *(float4*)&op[4] = make_float4(acc[r][4], acc[r][5], acc[r][6], acc[r][7]);
    }
}

extern "C" void kernel_launch(void* const* d_in, const int* in_sizes, int n_in,
                              void* d_out, int out_size, void* d_ws, size_t ws_size,
                              hipStream_t stream) {
    const float* x     = (const float*)d_in[0];
    const float* adj   = (const float*)d_in[1];
    const float* alpha = (const float*)d_in[2];
    const float* Watt  = (const float*)d_in[3];
    const float* Wout  = (const float*)d_in[4];
    float* out = (float*)d_out;

    float* ws    = (float*)d_ws;
    float* k     = ws;                 // 524288
    float* kq    = ws + 524288;        // 524288
    float* rmax  = ws + 1048576;       // 32768
    float* rrsum = ws + 1081344;       // 32768
    float* y     = ws + 1114112;       // 33554432  (total ~138.7 MB)

    kA<<<2048, 256, 0, stream>>>(x, alpha, Watt, k, kq);
    kB<<<32768, 256, 0, stream>>>(k, kq, rmax, rrsum);
    kC<<<8192, 256, 0, stream>>>(x, Wout, y);
    kD<<<dim3(16, 4, 32), 256, 0, stream>>>(k, kq, rmax, rrsum, adj, y, out);
}

// Round 2
// 298.021 us; speedup vs baseline: 15.1568x; 15.1568x over previous
//
#include <hip/hip_runtime.h>
#include <hip/hip_bf16.h>

// B=32, C_IN=64, C_OUT=64, N=1024, T=16
// Decomposition:
//  kA : k[b,n,t] = sum_i x*alpha ; kq = k @ W_att            (fp32)
//  kC : ybf[b,o,m,t] = sum_c W_out[o,c] x[b,c,m,t]           (bf16 out)
//  kT : Yt[b][j=o*16+t][m] = ybf[b][o][m][t]                 (transpose)
//  kBP: Pbf[b][n][m] = bf16( softmax_m(kq[n]·k[m]) * adj )   (A panel)
//  kD : out[b,o,n,t] = sum_m P[n,m] * Yt[j,m]   via bf16 MFMA GEMM

typedef float  f32x4 __attribute__((ext_vector_type(4)));
typedef short  s16x8 __attribute__((ext_vector_type(8)));
typedef unsigned short u16x8 __attribute__((ext_vector_type(8)));

static __device__ __forceinline__ unsigned short f2bf(float f) {
    __hip_bfloat16 h = __float2bfloat16(f);
    return *reinterpret_cast<unsigned short*>(&h);
}

__global__ __launch_bounds__(256) void kA(const float* __restrict__ x,
                                          const float* __restrict__ alpha,
                                          const float* __restrict__ Watt,
                                          float* __restrict__ kk_,
                                          float* __restrict__ kq_) {
    __shared__ float al[64];
    __shared__ float kl[16][17];
    __shared__ float wl[16][16];
    int tid = threadIdx.x;
    if (tid < 64) al[tid] = alpha[tid];
    int rl = tid >> 4, t = tid & 15;
    wl[rl][t] = Watt[tid];
    __syncthreads();
    size_t row = (size_t)blockIdx.x * 16 + rl;   // b*1024 + n
    int b = (int)(row >> 10);
    int n = (int)(row & 1023);
    const float* xp = x + (size_t)b * (64 * 16384) + (size_t)n * 16 + t;
    float acc = 0.f;
    #pragma unroll
    for (int i = 0; i < 64; ++i) acc = fmaf(xp[(size_t)i * 16384], al[i], acc);
    kl[rl][t] = acc;
    __syncthreads();
    float q = 0.f;
    #pragma unroll
    for (int s = 0; s < 16; ++s) q = fmaf(kl[rl][s], wl[s][t], q);
    kk_[row * 16 + t] = acc;
    kq_[row * 16 + t] = q;
}

// P panel: softmax(scores)*adj in bf16. One block = (b, 4 n-rows).
__global__ __launch_bounds__(256) void kBP(const float* __restrict__ kk_,
                                           const float* __restrict__ kq_,
                                           const float* __restrict__ adj,
                                           unsigned short* __restrict__ Pbf) {
    int tid = threadIdx.x;
    int b  = blockIdx.x >> 8;
    int n0 = (blockIdx.x & 255) * 4;
    __shared__ float kql[4][16];
    __shared__ float redm[4][4], reds[4][4];
    if (tid < 64)
        kql[tid >> 4][tid & 15] =
            kq_[((size_t)b * 1024 + n0 + (tid >> 4)) * 16 + (tid & 15)];
    __syncthreads();
    const float* kb = kk_ + (size_t)b * 16384;
    float kf[4][16];
    #pragma unroll
    for (int u = 0; u < 4; ++u) {
        const float* p = &kb[(size_t)(u * 256 + tid) * 16];
        #pragma unroll
        for (int s = 0; s < 16; ++s) kf[u][s] = p[s];
    }
    float sc[4][4];
    #pragma unroll
    for (int r = 0; r < 4; ++r)
        #pragma unroll
        for (int u = 0; u < 4; ++u) {
            float a = 0.f;
            #pragma unroll
            for (int s = 0; s < 16; ++s) a = fmaf(kql[r][s], kf[u][s], a);
            sc[r][u] = a;
        }
    float mx[4];
    #pragma unroll
    for (int r = 0; r < 4; ++r)
        mx[r] = fmaxf(fmaxf(sc[r][0], sc[r][1]), fmaxf(sc[r][2], sc[r][3]));
    #pragma unroll
    for (int off = 32; off; off >>= 1)
        #pragma unroll
        for (int r = 0; r < 4; ++r) mx[r] = fmaxf(mx[r], __shfl_xor(mx[r], off));
    int w = tid >> 6;
    if ((tid & 63) == 0)
        #pragma unroll
        for (int r = 0; r < 4; ++r) redm[w][r] = mx[r];
    __syncthreads();
    #pragma unroll
    for (int r = 0; r < 4; ++r)
        mx[r] = fmaxf(fmaxf(redm[0][r], redm[1][r]), fmaxf(redm[2][r], redm[3][r]));
    float e[4][4], se[4];
    #pragma unroll
    for (int r = 0; r < 4; ++r) {
        float s = 0.f;
        #pragma unroll
        for (int u = 0; u < 4; ++u) { e[r][u] = __expf(sc[r][u] - mx[r]); s += e[r][u]; }
        se[r] = s;
    }
    #pragma unroll
    for (int off = 32; off; off >>= 1)
        #pragma unroll
        for (int r = 0; r < 4; ++r) se[r] += __shfl_xor(se[r], off);
    if ((tid & 63) == 0)
        #pragma unroll
        for (int r = 0; r < 4; ++r) reds[w][r] = se[r];
    __syncthreads();
    float rrs[4];
    #pragma unroll
    for (int r = 0; r < 4; ++r)
        rrs[r] = 1.f / (reds[0][r] + reds[1][r] + reds[2][r] + reds[3][r]);
    #pragma unroll
    for (int r = 0; r < 4; ++r)
        #pragma unroll
        for (int u = 0; u < 4; ++u) {
            size_t m = (size_t)u * 256 + tid;
            float av = adj[(size_t)(n0 + r) * 1024 + m];
            Pbf[((size_t)b * 1024 + n0 + r) * 1024 + m] = f2bf(e[r][u] * rrs[r] * av);
        }
}

__global__ __launch_bounds__(256) void kC(const float* __restrict__ x,
                                          const float* __restrict__ Wout,
                                          unsigned short* __restrict__ ybf) {
    __shared__ __align__(16) float Xt[64][68];
    __shared__ __align__(16) float WT[64][68];   // WT[c][o]
    int tid = threadIdx.x;
    int b = blockIdx.x >> 8;
    int j0 = (blockIdx.x & 255) * 64;            // flat m*16+t
    #pragma unroll
    for (int it = 0; it < 16; ++it) {
        int idx = it * 256 + tid;
        int o = idx >> 6, c = idx & 63;
        WT[c][o] = Wout[idx];
        int c2 = it * 4 + (tid >> 6), j = tid & 63;
        Xt[c2][j] = x[(size_t)(b * 64 + c2) * 16384 + j0 + j];
    }
    __syncthreads();
    int oy = tid >> 4, jx = tid & 15;
    float acc[4][4] = {};
    #pragma unroll
    for (int c = 0; c < 64; ++c) {
        float4 w4 = *(const float4*)&WT[c][oy * 4];
        float4 x4 = *(const float4*)&Xt[c][jx * 4];
        float wv[4] = {w4.x, w4.y, w4.z, w4.w};
        float xv[4] = {x4.x, x4.y, x4.z, x4.w};
        #pragma unroll
        for (int u = 0; u < 4; ++u)
            #pragma unroll
            for (int v = 0; v < 4; ++v)
                acc[u][v] = fmaf(wv[u], xv[v], acc[u][v]);
    }
    #pragma unroll
    for (int u = 0; u < 4; ++u) {
        int o = oy * 4 + u;
        ushort4 w4 = make_ushort4(f2bf(acc[u][0]), f2bf(acc[u][1]),
                                  f2bf(acc[u][2]), f2bf(acc[u][3]));
        *(ushort4*)&ybf[(size_t)(b * 64 + o) * 16384 + j0 + jx * 4] = w4;
    }
}

// transpose ybf[b][o][m][t] -> Yt[b][j=o*16+t][m]
__global__ __launch_bounds__(256) void kT(const unsigned short* __restrict__ ybf,
                                          unsigned short* __restrict__ Yt) {
    __shared__ unsigned short Tl[64][72];
    int tid = threadIdx.x;
    int mc = blockIdx.x, oc = blockIdx.y, b = blockIdx.z;
    int oo = tid >> 6, mm = tid & 63;
    const unsigned short* src =
        ybf + ((size_t)(b * 64 + oc * 4 + oo) * 1024 + mc * 64 + mm) * 16;
    u16x8 v0 = *(const u16x8*)src;
    u16x8 v1 = *(const u16x8*)(src + 8);
    #pragma unroll
    for (int t = 0; t < 8; ++t) Tl[oo * 16 + t][mm] = v0[t];
    #pragma unroll
    for (int t = 0; t < 8; ++t) Tl[oo * 16 + 8 + t][mm] = v1[t];
    __syncthreads();
    int j = tid >> 2, ms = (tid & 3) * 16;
    u16x8 o0, o1;
    #pragma unroll
    for (int q = 0; q < 8; ++q) { o0[q] = Tl[j][ms + q]; o1[q] = Tl[j][ms + 8 + q]; }
    unsigned short* dst = Yt + (((size_t)b * 1024 + oc * 64 + j) << 10) + mc * 64 + ms;
    *(u16x8*)dst = o0;
    *(u16x8*)(dst + 8) = o1;
}

// out[b][j][n-block] GEMM: C[n][j] = sum_m P[n][m] * Yt[j][m], bf16 MFMA.
// 128x128 tile, BK=64, 4 waves, 4x4 16x16x32 frags per wave.
__global__ __launch_bounds__(256) void kD(const unsigned short* __restrict__ P,
                                          const unsigned short* __restrict__ Yt,
                                          float* __restrict__ out) {
    __shared__ __align__(16) unsigned short As[128][72];
    __shared__ __align__(16) unsigned short Bs[128][72];
    int tid = threadIdx.x;
    int b  = blockIdx.z;
    int n0 = blockIdx.x * 128;
    int j0 = blockIdx.y * 128;
    const unsigned short* Pb = P  + ((size_t)b << 20) + ((size_t)n0 << 10);
    const unsigned short* Yb = Yt + ((size_t)b << 20) + ((size_t)j0 << 10);
    int l = tid & 63, wv = tid >> 6;
    int wr = wv >> 1, wc = wv & 1;
    f32x4 acc[4][4] = {};
    for (int kt = 0; kt < 16; ++kt) {
        int k0 = kt * 64;
        #pragma unroll
        for (int it = 0; it < 4; ++it) {
            int id = it * 256 + tid;
            int r = id >> 3, kk = (id & 7) * 8;
            u16x8 av = *(const u16x8*)(Pb + ((size_t)r << 10) + k0 + kk);
            u16x8 bv = *(const u16x8*)(Yb + ((size_t)r << 10) + k0 + kk);
            *(u16x8*)&As[r][kk] = av;
            *(u16x8*)&Bs[r][kk] = bv;
        }
        __syncthreads();
        #pragma unroll
        for (int ks = 0; ks < 2; ++ks) {
            int ko = ks * 32 + (l >> 4) * 8;
            s16x8 af[4], bfr[4];
            #pragma unroll
            for (int mi = 0; mi < 4; ++mi)
                af[mi] = *(const s16x8*)&As[wr * 64 + mi * 16 + (l & 15)][ko];
            #pragma unroll
            for (int nj = 0; nj < 4; ++nj)
                bfr[nj] = *(const s16x8*)&Bs[wc * 64 + nj * 16 + (l & 15)][ko];
            #pragma unroll
            for (int mi = 0; mi < 4; ++mi)
                #pragma unroll
                for (int nj = 0; nj < 4; ++nj)
                    acc[mi][nj] = __builtin_amdgcn_mfma_f32_16x16x32_bf16(
                        af[mi], bfr[nj], acc[mi][nj], 0, 0, 0);
        }
        __syncthreads();
    }
    int t = l & 15;
    #pragma unroll
    for (int mi = 0; mi < 4; ++mi)
        #pragma unroll
        for (int nj = 0; nj < 4; ++nj) {
            int o  = (j0 >> 4) + wc * 4 + nj;
            int nb = n0 + wr * 64 + mi * 16 + (l >> 4) * 4;
            float* op = out + ((size_t)(b * 64 + o) << 14) + (size_t)nb * 16 + t;
            #pragma unroll
            for (int q = 0; q < 4; ++q) op[q * 16] = acc[mi][nj][q];
        }
}

extern "C" void kernel_launch(void* const* d_in, const int* in_sizes, int n_in,
                              void* d_out, int out_size, void* d_ws, size_t ws_size,
                              hipStream_t stream) {
    const float* x     = (const float*)d_in[0];
    const float* adj   = (const float*)d_in[1];
    const float* alpha = (const float*)d_in[2];
    const float* Watt  = (const float*)d_in[3];
    const float* Wout  = (const float*)d_in[4];
    float* out = (float*)d_out;

    char* ws = (char*)d_ws;
    float* k  = (float*)ws;                          // 2 MB
    float* kq = (float*)(ws + 2097152);              // 2 MB
    unsigned short* r1 = (unsigned short*)(ws + 4194304);              // 64 MB (ybf, then Pbf)
    unsigned short* r2 = (unsigned short*)(ws + 4194304 + 67108864);   // 64 MB (Yt)
    // total 138,412,032 B

    kA <<<2048, 256, 0, stream>>>(x, alpha, Watt, k, kq);
    kC <<<8192, 256, 0, stream>>>(x, Wout, r1);              // r1 = ybf
    kT <<<dim3(16, 16, 32), 256, 0, stream>>>(r1, r2);       // r2 = Yt
    kBP<<<8192, 256, 0, stream>>>(k, kq, adj, r1);           // r1 = Pbf (ybf dead)
    kD <<<dim3(8, 8, 32), 256, 0, stream>>>(r1, r2, out);
}

// Round 3
// 261.564 us; speedup vs baseline: 17.2694x; 1.1394x over previous
//
#include <hip/hip_runtime.h>
#include <hip/hip_bf16.h>

// B=32, C_IN=64, C_OUT=64, N=1024, T=16
//  kCF: ybf[b,o,m,t] = sum_c W_out[o,c] x[b,c,m,t]  (bf16)  + k,kq (fused kA)
//  kT : Yt[b][j=o*16+t][m] = ybf[b][o][m][t]
//  kBP: Pbf[b][n][m] = bf16( softmax_m(kq[n]·k[m]) * adj )
//  kD : out[b,o,n,t] = sum_m P[n,m]*Yt[j,m]  — bf16 MFMA, m97 structure
//       (global_load_lds 16B, linear LDS, XCD-grouped blocks)

typedef float  f32x4 __attribute__((ext_vector_type(4)));
typedef short  s16x8 __attribute__((ext_vector_type(8)));
typedef unsigned short u16x8 __attribute__((ext_vector_type(8)));

#define GLOAD_LDS16(g, l) __builtin_amdgcn_global_load_lds(                    \
    (const __attribute__((address_space(1))) void*)(g),                        \
    (__attribute__((address_space(3))) void*)(l), 16, 0, 0)

static __device__ __forceinline__ unsigned short f2bf(float f) {
    __hip_bfloat16 h = __float2bfloat16(f);
    return *reinterpret_cast<unsigned short*>(&h);
}

// Fused kA+kC: per block (b, 64 flat j = 4 m x 16 t)
__global__ __launch_bounds__(256) void kCF(const float* __restrict__ x,
                                           const float* __restrict__ Wout,
                                           const float* __restrict__ alpha,
                                           const float* __restrict__ Watt,
                                           unsigned short* __restrict__ ybf,
                                           float* __restrict__ kk_,
                                           float* __restrict__ kq_) {
    __shared__ __align__(16) float Xt[64][68];
    __shared__ __align__(16) float WT[64][68];   // WT[c][o]
    __shared__ float al[64];
    __shared__ float wl[16][17];
    __shared__ float kl[64];
    int tid = threadIdx.x;
    int b = blockIdx.x >> 8;
    int j0 = (blockIdx.x & 255) * 64;            // flat m*16+t
    if (tid < 64) al[tid] = alpha[tid];
    wl[tid >> 4][tid & 15] = Watt[tid];
    #pragma unroll
    for (int it = 0; it < 16; ++it) {
        int idx = it * 256 + tid;
        int o = idx >> 6, c = idx & 63;
        WT[c][o] = Wout[idx];
        int c2 = it * 4 + (tid >> 6), j = tid & 63;
        Xt[c2][j] = x[(size_t)(b * 64 + c2) * 16384 + j0 + j];
    }
    __syncthreads();
    int oy = tid >> 4, jx = tid & 15;
    float acc[4][4] = {};
    #pragma unroll
    for (int c = 0; c < 64; ++c) {
        float4 w4 = *(const float4*)&WT[c][oy * 4];
        float4 x4 = *(const float4*)&Xt[c][jx * 4];
        float wv[4] = {w4.x, w4.y, w4.z, w4.w};
        float xv[4] = {x4.x, x4.y, x4.z, x4.w};
        #pragma unroll
        for (int u = 0; u < 4; ++u)
            #pragma unroll
            for (int v = 0; v < 4; ++v)
                acc[u][v] = fmaf(wv[u], xv[v], acc[u][v]);
    }
    #pragma unroll
    for (int u = 0; u < 4; ++u) {
        int o = oy * 4 + u;
        ushort4 w4 = make_ushort4(f2bf(acc[u][0]), f2bf(acc[u][1]),
                                  f2bf(acc[u][2]), f2bf(acc[u][3]));
        *(ushort4*)&ybf[(size_t)(b * 64 + o) * 16384 + j0 + jx * 4] = w4;
    }
    // fused kA: k[j] = sum_c alpha[c]*x[c][j] ; kq = k @ W_att
    if (tid < 64) {
        float kv = 0.f;
        #pragma unroll
        for (int c = 0; c < 64; ++c) kv = fmaf(al[c], Xt[c][tid], kv);
        kl[tid] = kv;
    }
    __syncthreads();
    if (tid < 64) {
        int mq = tid >> 4, tq = tid & 15;
        float q = 0.f;
        #pragma unroll
        for (int s = 0; s < 16; ++s) q = fmaf(kl[mq * 16 + s], wl[s][tq], q);
        size_t gj = (size_t)b * 16384 + j0 + tid;
        kk_[gj] = kl[tid];
        kq_[gj] = q;
    }
}

// P panel: softmax(scores)*adj in bf16. One block = (b, 4 n-rows).
__global__ __launch_bounds__(256) void kBP(const float* __restrict__ kk_,
                                           const float* __restrict__ kq_,
                                           const float* __restrict__ adj,
                                           unsigned short* __restrict__ Pbf) {
    int tid = threadIdx.x;
    int b  = blockIdx.x >> 8;
    int n0 = (blockIdx.x & 255) * 4;
    __shared__ float kql[4][16];
    __shared__ float redm[4][4], reds[4][4];
    if (tid < 64)
        kql[tid >> 4][tid & 15] =
            kq_[((size_t)b * 1024 + n0 + (tid >> 4)) * 16 + (tid & 15)];
    __syncthreads();
    const float* kb = kk_ + (size_t)b * 16384;
    float kf[4][16];
    #pragma unroll
    for (int u = 0; u < 4; ++u) {
        const float* p = &kb[(size_t)(u * 256 + tid) * 16];
        #pragma unroll
        for (int s = 0; s < 16; ++s) kf[u][s] = p[s];
    }
    float sc[4][4];
    #pragma unroll
    for (int r = 0; r < 4; ++r)
        #pragma unroll
        for (int u = 0; u < 4; ++u) {
            float a = 0.f;
            #pragma unroll
            for (int s = 0; s < 16; ++s) a = fmaf(kql[r][s], kf[u][s], a);
            sc[r][u] = a;
        }
    float mx[4];
    #pragma unroll
    for (int r = 0; r < 4; ++r)
        mx[r] = fmaxf(fmaxf(sc[r][0], sc[r][1]), fmaxf(sc[r][2], sc[r][3]));
    #pragma unroll
    for (int off = 32; off; off >>= 1)
        #pragma unroll
        for (int r = 0; r < 4; ++r) mx[r] = fmaxf(mx[r], __shfl_xor(mx[r], off));
    int w = tid >> 6;
    if ((tid & 63) == 0)
        #pragma unroll
        for (int r = 0; r < 4; ++r) redm[w][r] = mx[r];
    __syncthreads();
    #pragma unroll
    for (int r = 0; r < 4; ++r)
        mx[r] = fmaxf(fmaxf(redm[0][r], redm[1][r]), fmaxf(redm[2][r], redm[3][r]));
    float e[4][4], se[4];
    #pragma unroll
    for (int r = 0; r < 4; ++r) {
        float s = 0.f;
        #pragma unroll
        for (int u = 0; u < 4; ++u) { e[r][u] = __expf(sc[r][u] - mx[r]); s += e[r][u]; }
        se[r] = s;
    }
    #pragma unroll
    for (int off = 32; off; off >>= 1)
        #pragma unroll
        for (int r = 0; r < 4; ++r) se[r] += __shfl_xor(se[r], off);
    if ((tid & 63) == 0)
        #pragma unroll
        for (int r = 0; r < 4; ++r) reds[w][r] = se[r];
    __syncthreads();
    float rrs[4];
    #pragma unroll
    for (int r = 0; r < 4; ++r)
        rrs[r] = 1.f / (reds[0][r] + reds[1][r] + reds[2][r] + reds[3][r]);
    #pragma unroll
    for (int r = 0; r < 4; ++r)
        #pragma unroll
        for (int u = 0; u < 4; ++u) {
            size_t m = (size_t)u * 256 + tid;
            float av = adj[(size_t)(n0 + r) * 1024 + m];
            Pbf[((size_t)b * 1024 + n0 + r) * 1024 + m] = f2bf(e[r][u] * rrs[r] * av);
        }
}

// transpose ybf[b][o][m][t] -> Yt[b][j=o*16+t][m]
__global__ __launch_bounds__(256) void kT(const unsigned short* __restrict__ ybf,
                                          unsigned short* __restrict__ Yt) {
    __shared__ unsigned short Tl[64][72];
    int tid = threadIdx.x;
    int mc = blockIdx.x, oc = blockIdx.y, b = blockIdx.z;
    int oo = tid >> 6, mm = tid & 63;
    const unsigned short* src =
        ybf + ((size_t)(b * 64 + oc * 4 + oo) * 1024 + mc * 64 + mm) * 16;
    u16x8 v0 = *(const u16x8*)src;
    u16x8 v1 = *(const u16x8*)(src + 8);
    #pragma unroll
    for (int t = 0; t < 8; ++t) Tl[oo * 16 + t][mm] = v0[t];
    #pragma unroll
    for (int t = 0; t < 8; ++t) Tl[oo * 16 + 8 + t][mm] = v1[t];
    __syncthreads();
    int j = tid >> 2, ms = (tid & 3) * 16;
    u16x8 o0, o1;
    #pragma unroll
    for (int q = 0; q < 8; ++q) { o0[q] = Tl[j][ms + q]; o1[q] = Tl[j][ms + 8 + q]; }
    unsigned short* dst = Yt + (((size_t)b * 1024 + oc * 64 + j) << 10) + mc * 64 + ms;
    *(u16x8*)dst = o0;
    *(u16x8*)(dst + 8) = o1;
}

// GEMM: C[n][j] = sum_m P[n][m] * Yt[j][m]; 128x128 tile, BK=64, m97-style.
__global__ __launch_bounds__(256) void kD(const unsigned short* __restrict__ P,
                                          const unsigned short* __restrict__ Yt,
                                          float* __restrict__ out) {
    __shared__ __align__(16) unsigned short As[128 * 64];
    __shared__ __align__(16) unsigned short Bs[128 * 64];
    // XCD-grouped swizzle: 2048 blocks, XCD x gets wgid [x*256, x*256+256)
    int bid = blockIdx.x;
    int wgid = (bid & 7) * 256 + (bid >> 3);
    int b    = wgid >> 6;
    int rem  = wgid & 63;
    int n0 = (rem & 7) * 128;
    int j0 = (rem >> 3) * 128;
    int tid = threadIdx.x;
    const unsigned short* Pb = P  + ((size_t)b << 20) + ((size_t)n0 << 10);
    const unsigned short* Yb = Yt + ((size_t)b << 20) + ((size_t)j0 << 10);
    int l = tid & 63, w = tid >> 6;
    int wr = w >> 1, wc = w & 1;
    f32x4 acc[4][4] = {};
    for (int kt = 0; kt < 16; ++kt) {
        int k0 = kt << 6;
        #pragma unroll
        for (int s = 0; s < 4; ++s) {
            int row = (w << 5) + (s << 3) + (l >> 3);
            size_t go = ((size_t)row << 10) + k0 + ((l & 7) << 3);
            int lo = ((w << 2) + s) << 9;     // ushort offset of 1KB segment
            GLOAD_LDS16(Pb + go, &As[lo]);
            GLOAD_LDS16(Yb + go, &Bs[lo]);
        }
        __syncthreads();
        #pragma unroll
        for (int ks = 0; ks < 2; ++ks) {
            int ko = ks * 32 + (l >> 4) * 8;
            s16x8 af[4], bfr[4];
            #pragma unroll
            for (int mi = 0; mi < 4; ++mi)
                af[mi] = *(const s16x8*)&As[(wr * 64 + mi * 16 + (l & 15)) * 64 + ko];
            #pragma unroll
            for (int nj = 0; nj < 4; ++nj)
                bfr[nj] = *(const s16x8*)&Bs[(wc * 64 + nj * 16 + (l & 15)) * 64 + ko];
            #pragma unroll
            for (int mi = 0; mi < 4; ++mi)
                #pragma unroll
                for (int nj = 0; nj < 4; ++nj)
                    acc[mi][nj] = __builtin_amdgcn_mfma_f32_16x16x32_bf16(
                        af[mi], bfr[nj], acc[mi][nj], 0, 0, 0);
        }
        __syncthreads();
    }
    int t = l & 15;
    #pragma unroll
    for (int mi = 0; mi < 4; ++mi)
        #pragma unroll
        for (int nj = 0; nj < 4; ++nj) {
            int o  = (j0 >> 4) + wc * 4 + nj;
            int nb = n0 + wr * 64 + mi * 16 + (l >> 4) * 4;
            float* op = out + ((size_t)(b * 64 + o) << 14) + (size_t)nb * 16 + t;
            #pragma unroll
            for (int q = 0; q < 4; ++q) op[q * 16] = acc[mi][nj][q];
        }
}

extern "C" void kernel_launch(void* const* d_in, const int* in_sizes, int n_in,
                              void* d_out, int out_size, void* d_ws, size_t ws_size,
                              hipStream_t stream) {
    const float* x     = (const float*)d_in[0];
    const float* adj   = (const float*)d_in[1];
    const float* alpha = (const float*)d_in[2];
    const float* Watt  = (const float*)d_in[3];
    const float* Wout  = (const float*)d_in[4];
    float* out = (float*)d_out;

    char* ws = (char*)d_ws;
    float* k  = (float*)ws;                          // 2 MB
    float* kq = (float*)(ws + 2097152);              // 2 MB
    unsigned short* r1 = (unsigned short*)(ws + 4194304);              // 64 MB (ybf -> Pbf)
    unsigned short* r2 = (unsigned short*)(ws + 4194304 + 67108864);   // 64 MB (Yt)

    kCF<<<8192, 256, 0, stream>>>(x, Wout, alpha, Watt, r1, k, kq);   // r1 = ybf
    kT <<<dim3(16, 16, 32), 256, 0, stream>>>(r1, r2);                // r2 = Yt
    kBP<<<8192, 256, 0, stream>>>(k, kq, adj, r1);                    // r1 = Pbf
    kD <<<2048, 256, 0, stream>>>(r1, r2, out);
}

// Round 4
// 233.975 us; speedup vs baseline: 19.3057x; 1.1179x over previous
//
#include <hip/hip_runtime.h>
#include <hip/hip_bf16.h>

// B=32, C_IN=64, C_OUT=64, N=1024, T=16
//  kCF: ybf[b,o,m,t] = sum_c W_out[o,c] x[b,c,m,t]  (bf16)  + k,kq (fused kA)
//  kT : Yt[b][j=o*16+t][m] = ybf[b][o][m][t]
//  kBP: Pbf[b][n][m] = bf16( softmax_m(kq[n]·k[m]) * adj )
//  kD : out[b,o,n,t] = sum_m P[n,m]*Yt[j,m]
//       256x256 tile, BK=64, 8 waves, 4-phase schedule, T2 src-swizzle,
//       global_load_lds(16B), counted-by-structure prefetch, T5 setprio.

typedef float  f32x4 __attribute__((ext_vector_type(4)));
typedef short  s16x8 __attribute__((ext_vector_type(8)));
typedef unsigned short u16x8 __attribute__((ext_vector_type(8)));

#define GLOAD_LDS16(g, l) __builtin_amdgcn_global_load_lds(                    \
    (const __attribute__((address_space(1))) void*)(g),                        \
    (__attribute__((address_space(3))) void*)(l), 16, 0, 0)

static __device__ __forceinline__ unsigned short f2bf(float f) {
    __hip_bfloat16 h = __float2bfloat16(f);
    return *reinterpret_cast<unsigned short*>(&h);
}

// Fused kA+kC: per block (b, 64 flat j = 4 m x 16 t)
__global__ __launch_bounds__(256) void kCF(const float* __restrict__ x,
                                           const float* __restrict__ Wout,
                                           const float* __restrict__ alpha,
                                           const float* __restrict__ Watt,
                                           unsigned short* __restrict__ ybf,
                                           float* __restrict__ kk_,
                                           float* __restrict__ kq_) {
    __shared__ __align__(16) float Xt[64][68];
    __shared__ __align__(16) float WT[64][68];   // WT[c][o]
    __shared__ float al[64];
    __shared__ float wl[16][17];
    __shared__ float kl[64];
    int tid = threadIdx.x;
    int b = blockIdx.x >> 8;
    int j0 = (blockIdx.x & 255) * 64;            // flat m*16+t
    if (tid < 64) al[tid] = alpha[tid];
    wl[tid >> 4][tid & 15] = Watt[tid];
    #pragma unroll
    for (int it = 0; it < 16; ++it) {
        int idx = it * 256 + tid;
        int o = idx >> 6, c = idx & 63;
        WT[c][o] = Wout[idx];
        int c2 = it * 4 + (tid >> 6), j = tid & 63;
        Xt[c2][j] = x[(size_t)(b * 64 + c2) * 16384 + j0 + j];
    }
    __syncthreads();
    int oy = tid >> 4, jx = tid & 15;
    float acc[4][4] = {};
    #pragma unroll
    for (int c = 0; c < 64; ++c) {
        float4 w4 = *(const float4*)&WT[c][oy * 4];
        float4 x4 = *(const float4*)&Xt[c][jx * 4];
        float wv[4] = {w4.x, w4.y, w4.z, w4.w};
        float xv[4] = {x4.x, x4.y, x4.z, x4.w};
        #pragma unroll
        for (int u = 0; u < 4; ++u)
            #pragma unroll
            for (int v = 0; v < 4; ++v)
                acc[u][v] = fmaf(wv[u], xv[v], acc[u][v]);
    }
    #pragma unroll
    for (int u = 0; u < 4; ++u) {
        int o = oy * 4 + u;
        ushort4 w4 = make_ushort4(f2bf(acc[u][0]), f2bf(acc[u][1]),
                                  f2bf(acc[u][2]), f2bf(acc[u][3]));
        *(ushort4*)&ybf[(size_t)(b * 64 + o) * 16384 + j0 + jx * 4] = w4;
    }
    if (tid < 64) {
        float kv = 0.f;
        #pragma unroll
        for (int c = 0; c < 64; ++c) kv = fmaf(al[c], Xt[c][tid], kv);
        kl[tid] = kv;
    }
    __syncthreads();
    if (tid < 64) {
        int mq = tid >> 4, tq = tid & 15;
        float q = 0.f;
        #pragma unroll
        for (int s = 0; s < 16; ++s) q = fmaf(kl[mq * 16 + s], wl[s][tq], q);
        size_t gj = (size_t)b * 16384 + j0 + tid;
        kk_[gj] = kl[tid];
        kq_[gj] = q;
    }
}

// P panel: softmax(scores)*adj in bf16. One block = (b, 4 n-rows).
__global__ __launch_bounds__(256) void kBP(const float* __restrict__ kk_,
                                           const float* __restrict__ kq_,
                                           const float* __restrict__ adj,
                                           unsigned short* __restrict__ Pbf) {
    int tid = threadIdx.x;
    int b  = blockIdx.x >> 8;
    int n0 = (blockIdx.x & 255) * 4;
    __shared__ float kql[4][16];
    __shared__ float redm[4][4], reds[4][4];
    if (tid < 64)
        kql[tid >> 4][tid & 15] =
            kq_[((size_t)b * 1024 + n0 + (tid >> 4)) * 16 + (tid & 15)];
    __syncthreads();
    const float* kb = kk_ + (size_t)b * 16384;
    float kf[4][16];
    #pragma unroll
    for (int u = 0; u < 4; ++u) {
        const float* p = &kb[(size_t)(u * 256 + tid) * 16];
        #pragma unroll
        for (int s = 0; s < 16; ++s) kf[u][s] = p[s];
    }
    float sc[4][4];
    #pragma unroll
    for (int r = 0; r < 4; ++r)
        #pragma unroll
        for (int u = 0; u < 4; ++u) {
            float a = 0.f;
            #pragma unroll
            for (int s = 0; s < 16; ++s) a = fmaf(kql[r][s], kf[u][s], a);
            sc[r][u] = a;
        }
    float mx[4];
    #pragma unroll
    for (int r = 0; r < 4; ++r)
        mx[r] = fmaxf(fmaxf(sc[r][0], sc[r][1]), fmaxf(sc[r][2], sc[r][3]));
    #pragma unroll
    for (int off = 32; off; off >>= 1)
        #pragma unroll
        for (int r = 0; r < 4; ++r) mx[r] = fmaxf(mx[r], __shfl_xor(mx[r], off));
    int w = tid >> 6;
    if ((tid & 63) == 0)
        #pragma unroll
        for (int r = 0; r < 4; ++r) redm[w][r] = mx[r];
    __syncthreads();
    #pragma unroll
    for (int r = 0; r < 4; ++r)
        mx[r] = fmaxf(fmaxf(redm[0][r], redm[1][r]), fmaxf(redm[2][r], redm[3][r]));
    float e[4][4], se[4];
    #pragma unroll
    for (int r = 0; r < 4; ++r) {
        float s = 0.f;
        #pragma unroll
        for (int u = 0; u < 4; ++u) { e[r][u] = __expf(sc[r][u] - mx[r]); s += e[r][u]; }
        se[r] = s;
    }
    #pragma unroll
    for (int off = 32; off; off >>= 1)
        #pragma unroll
        for (int r = 0; r < 4; ++r) se[r] += __shfl_xor(se[r], off);
    if ((tid & 63) == 0)
        #pragma unroll
        for (int r = 0; r < 4; ++r) reds[w][r] = se[r];
    __syncthreads();
    float rrs[4];
    #pragma unroll
    for (int r = 0; r < 4; ++r)
        rrs[r] = 1.f / (reds[0][r] + reds[1][r] + reds[2][r] + reds[3][r]);
    #pragma unroll
    for (int r = 0; r < 4; ++r)
        #pragma unroll
        for (int u = 0; u < 4; ++u) {
            size_t m = (size_t)u * 256 + tid;
            float av = adj[(size_t)(n0 + r) * 1024 + m];
            Pbf[((size_t)b * 1024 + n0 + r) * 1024 + m] = f2bf(e[r][u] * rrs[r] * av);
        }
}

// transpose ybf[b][o][m][t] -> Yt[b][j=o*16+t][m]
__global__ __launch_bounds__(256) void kT(const unsigned short* __restrict__ ybf,
                                          unsigned short* __restrict__ Yt) {
    __shared__ unsigned short Tl[64][72];
    int tid = threadIdx.x;
    int mc = blockIdx.x, oc = blockIdx.y, b = blockIdx.z;
    int oo = tid >> 6, mm = tid & 63;
    const unsigned short* src =
        ybf + ((size_t)(b * 64 + oc * 4 + oo) * 1024 + mc * 64 + mm) * 16;
    u16x8 v0 = *(const u16x8*)src;
    u16x8 v1 = *(const u16x8*)(src + 8);
    #pragma unroll
    for (int t = 0; t < 8; ++t) Tl[oo * 16 + t][mm] = v0[t];
    #pragma unroll
    for (int t = 0; t < 8; ++t) Tl[oo * 16 + 8 + t][mm] = v1[t];
    __syncthreads();
    int j = tid >> 2, ms = (tid & 3) * 16;
    u16x8 o0, o1;
    #pragma unroll
    for (int q = 0; q < 8; ++q) { o0[q] = Tl[j][ms + q]; o1[q] = Tl[j][ms + 8 + q]; }
    unsigned short* dst = Yt + (((size_t)b * 1024 + oc * 64 + j) << 10) + mc * 64 + ms;
    *(u16x8*)dst = o0;
    *(u16x8*)(dst + 8) = o1;
}

// stage one 256x64 K-tile of A(P) and B(Yt) into LDS buffer `buf`
// (source chunk pre-swizzled: chunk ^= row&7; LDS dest linear)
static __device__ __forceinline__ void stage_tile(const unsigned short* Pb,
                                                  const unsigned short* Yb,
                                                  unsigned short* lds, int buf,
                                                  int kt, int ww, int l) {
    int r8  = (l >> 3) & 7;
    int glc = ((l & 7) ^ r8) << 3;       // swizzled source k-offset (ushorts)
    int k0  = kt << 6;
    unsigned short* base = lds + buf * 32768;
    #pragma unroll
    for (int s = 0; s < 4; ++s) {
        int row  = s * 64 + ww * 8;                       // wave-uniform
        size_t g = ((size_t)(row + r8) << 10) + k0 + glc; // per-lane
        GLOAD_LDS16(Pb + g, base + row * 64);
        GLOAD_LDS16(Yb + g, base + 16384 + row * 64);
    }
}

static __device__ __forceinline__ s16x8 frag_ld(const unsigned short* base,
                                                int R, int kc, int l7) {
    return *(const s16x8*)(base + R * 64 + ((kc ^ l7) << 3));
}

// GEMM: C[n][j] = sum_m P[n][m] * Yt[j][m]
__global__ __launch_bounds__(512, 2) void kD(const unsigned short* __restrict__ P,
                                             const unsigned short* __restrict__ Yt,
                                             float* __restrict__ out) {
    extern __shared__ unsigned short lds[];   // 2 * (256*64 A + 256*64 B) = 128 KiB
    // XCD-grouped mapping: 512 blocks, XCD x owns batches [x*4, x*4+4)
    int bid = blockIdx.x;
    int wg  = (bid & 7) * 64 + (bid >> 3);
    int b   = wg >> 4;
    int rem = wg & 15;
    int n0  = (rem & 3) << 8;
    int j0  = (rem >> 2) << 8;
    int tid = threadIdx.x;
    int l = tid & 63, ww = tid >> 6;
    int wr = ww >> 2, wc = ww & 3;       // 2 x 4 wave grid
    int l15 = l & 15, lhi = l >> 4, l7 = l & 7;
    const unsigned short* Pb = P  + ((size_t)b << 20) + ((size_t)n0 << 10);
    const unsigned short* Yb = Yt + ((size_t)b << 20) + ((size_t)j0 << 10);

    f32x4 acc[8][4] = {};
    stage_tile(Pb, Yb, lds, 0, 0, ww, l);
    __syncthreads();

    for (int kt = 0; kt < 16; ++kt) {
        int cur = kt & 1;
        const unsigned short* Ab = lds + cur * 32768;
        const unsigned short* Bb = Ab + 16384;
        s16x8 bf[4][2];
        #pragma unroll
        for (int q = 0; q < 4; ++q) {
            if (q == 0) {
                int ktn = kt < 15 ? kt + 1 : 15;
                stage_tile(Pb, Yb, lds, cur ^ 1, ktn, ww, l);
                #pragma unroll
                for (int nj = 0; nj < 4; ++nj)
                    #pragma unroll
                    for (int ks = 0; ks < 2; ++ks)
                        bf[nj][ks] = frag_ld(Bb, wc * 64 + nj * 16 + l15,
                                             ks * 4 + lhi, l7);
            }
            s16x8 af[2][2];
            #pragma unroll
            for (int mi = 0; mi < 2; ++mi)
                #pragma unroll
                for (int ks = 0; ks < 2; ++ks)
                    af[mi][ks] = frag_ld(Ab, wr * 128 + (q * 2 + mi) * 16 + l15,
                                         ks * 4 + lhi, l7);
            __builtin_amdgcn_s_barrier();
            asm volatile("s_waitcnt lgkmcnt(0)" ::: "memory");
            __builtin_amdgcn_sched_barrier(0);
            __builtin_amdgcn_s_setprio(1);
            #pragma unroll
            for (int mi = 0; mi < 2; ++mi)
                #pragma unroll
                for (int nj = 0; nj < 4; ++nj)
                    #pragma unroll
                    for (int ks = 0; ks < 2; ++ks)
                        acc[q * 2 + mi][nj] = __builtin_amdgcn_mfma_f32_16x16x32_bf16(
                            af[mi][ks], bf[nj][ks], acc[q * 2 + mi][nj], 0, 0, 0);
            __builtin_amdgcn_s_setprio(0);
            if (q < 3) __builtin_amdgcn_s_barrier();
        }
        __syncthreads();   // tile end: drain vmcnt (prefetch landed) + barrier
    }

    #pragma unroll
    for (int mi = 0; mi < 8; ++mi)
        #pragma unroll
        for (int nj = 0; nj < 4; ++nj) {
            int o  = (j0 >> 4) + wc * 4 + nj;
            int nb = n0 + wr * 128 + mi * 16 + lhi * 4;
            float* op = out + ((size_t)(b * 64 + o) << 14) + (size_t)nb * 16 + l15;
            #pragma unroll
            for (int q = 0; q < 4; ++q) op[q * 16] = acc[mi][nj][q];
        }
}

extern "C" void kernel_launch(void* const* d_in, const int* in_sizes, int n_in,
                              void* d_out, int out_size, void* d_ws, size_t ws_size,
                              hipStream_t stream) {
    const float* x     = (const float*)d_in[0];
    const float* adj   = (const float*)d_in[1];
    const float* alpha = (const float*)d_in[2];
    const float* Watt  = (const float*)d_in[3];
    const float* Wout  = (const float*)d_in[4];
    float* out = (float*)d_out;

    char* ws = (char*)d_ws;
    float* k  = (float*)ws;                          // 2 MB
    float* kq = (float*)(ws + 2097152);              // 2 MB
    unsigned short* r1 = (unsigned short*)(ws + 4194304);              // 64 MB (ybf -> Pbf)
    unsigned short* r2 = (unsigned short*)(ws + 4194304 + 67108864);   // 64 MB (Yt)

    kCF<<<8192, 256, 0, stream>>>(x, Wout, alpha, Watt, r1, k, kq);   // r1 = ybf
    kT <<<dim3(16, 16, 32), 256, 0, stream>>>(r1, r2);                // r2 = Yt
    kBP<<<8192, 256, 0, stream>>>(k, kq, adj, r1);                    // r1 = Pbf
    kD <<<512, 512, 131072, stream>>>(r1, r2, out);
}

// Round 5
// 201.995 us; speedup vs baseline: 22.3622x; 1.1583x over previous
//
#include <hip/hip_runtime.h>
#include <hip/hip_bf16.h>

// B=32, C_IN=64, C_OUT=64, N=1024, T=16
//  kCM: fused kA+kC+kT — MFMA y=W_out@x (bf16), write Yt[b][j=o*16+t][m]
//       directly (LDS bounce), plus k,kq fp32.
//  kBP: Pbf[b][n][m] = bf16( softmax_m(kq[n]·k[m]) * adj )
//  kD : out = P@Yt — 256x256, BK=32, triple-buffered LDS, counted vmcnt(4),
//       2 phases/tile, T5 setprio, XCD-grouped blocks.

typedef float  f32x4 __attribute__((ext_vector_type(4)));
typedef short  s16x8 __attribute__((ext_vector_type(8)));
typedef unsigned short u16x8 __attribute__((ext_vector_type(8)));

#define GLOAD_LDS16(g, l) __builtin_amdgcn_global_load_lds(                    \
    (const __attribute__((address_space(1))) void*)(g),                        \
    (__attribute__((address_space(3))) void*)(l), 16, 0, 0)

static __device__ __forceinline__ unsigned short f2bf(float f) {
    __hip_bfloat16 h = __float2bfloat16(f);
    return *reinterpret_cast<unsigned short*>(&h);
}

// ---------------- kCM: fused y-GEMM + transpose + k/kq ----------------
// block = (b, 16 m = 256 j). LDS: xt f32[64][260] (66560 B) reused as
// Ys u16[256][72] (36864 B); Wb u16[64][72] @66560; al @75776; wl @76032;
// kl @77120. total 78144 B dynamic.
__global__ __launch_bounds__(256) void kCM(const float* __restrict__ x,
                                           const float* __restrict__ Wout,
                                           const float* __restrict__ alpha,
                                           const float* __restrict__ Watt,
                                           unsigned short* __restrict__ Yt,
                                           float* __restrict__ kk_,
                                           float* __restrict__ kq_) {
    extern __shared__ char sm[];
    float* xt = (float*)sm;                              // [64][260]
    unsigned short* Ys = (unsigned short*)sm;            // [256][72] (after xt dead)
    unsigned short* Wb = (unsigned short*)(sm + 66560);  // [64][72]
    float* al = (float*)(sm + 75776);
    float* wl = (float*)(sm + 76032);                    // [16][17]
    float* kl = (float*)(sm + 77120);                    // [256]
    int tid = threadIdx.x;
    int b  = blockIdx.x >> 6;
    int mc = blockIdx.x & 63;
    int j0 = mc << 8;
    int m0 = mc << 4;
    if (tid < 64) al[tid] = alpha[tid];
    wl[(tid >> 4) * 17 + (tid & 15)] = Watt[tid];
    #pragma unroll
    for (int it = 0; it < 16; ++it) {
        int idx = it * 256 + tid;
        Wb[(idx >> 6) * 72 + (idx & 63)] = f2bf(Wout[idx]);
    }
    const float* xb = x + (size_t)b * (64 * 16384) + j0;
    #pragma unroll
    for (int it = 0; it < 16; ++it) {
        int idx = it * 256 + tid;
        int c = idx >> 6, j4 = (idx & 63) << 2;
        float4 v = *(const float4*)(xb + (size_t)c * 16384 + j4);
        *(float4*)&xt[c * 260 + j4] = v;
    }
    __syncthreads();
    int w = tid >> 6, l = tid & 63;
    int l15 = l & 15, lhi = l >> 4;
    int jw = w << 6;
    f32x4 acc[4][4] = {};
    s16x8 af[4][2];
    #pragma unroll
    for (int fro = 0; fro < 4; ++fro)
        #pragma unroll
        for (int ks = 0; ks < 2; ++ks)
            af[fro][ks] = *(const s16x8*)&Wb[(fro * 16 + l15) * 72 + ks * 32 + lhi * 8];
    #pragma unroll
    for (int fc = 0; fc < 4; ++fc) {
        #pragma unroll
        for (int ks = 0; ks < 2; ++ks) {
            int jcol = jw + fc * 16 + l15;
            int cb = ks * 32 + lhi * 8;
            s16x8 bf;
            #pragma unroll
            for (int e = 0; e < 8; ++e)
                bf[e] = (short)f2bf(xt[(cb + e) * 260 + jcol]);
            #pragma unroll
            for (int fro = 0; fro < 4; ++fro)
                acc[fro][fc] = __builtin_amdgcn_mfma_f32_16x16x32_bf16(
                    af[fro][ks], bf, acc[fro][fc], 0, 0, 0);
        }
    }
    // k (fp32, from fp32 xt — precision path unchanged)
    {
        float kv = 0.f;
        #pragma unroll
        for (int c = 0; c < 64; ++c) kv = fmaf(al[c], xt[c * 260 + tid], kv);
        kl[tid] = kv;
        kk_[(size_t)b * 16384 + j0 + tid] = kv;
    }
    __syncthreads();   // kl ready; xt dead below this point
    {
        int ml = tid >> 4, tq = tid & 15;
        float q = 0.f;
        #pragma unroll
        for (int s = 0; s < 16; ++s) q = fmaf(kl[ml * 16 + s], wl[s * 17 + tq], q);
        kq_[(size_t)b * 16384 + j0 + tid] = q;
    }
    // C frags -> Ys[j_local][o] (bf16), overlapping dead xt
    #pragma unroll
    for (int fro = 0; fro < 4; ++fro)
        #pragma unroll
        for (int fc = 0; fc < 4; ++fc) {
            int jl = jw + fc * 16 + l15;
            int o0 = fro * 16 + lhi * 4;
            ushort4 pk = make_ushort4(f2bf(acc[fro][fc][0]), f2bf(acc[fro][fc][1]),
                                      f2bf(acc[fro][fc][2]), f2bf(acc[fro][fc][3]));
            *(ushort4*)&Ys[jl * 72 + o0] = pk;
        }
    __syncthreads();
    // Yt[b][r=o*16+t][m0+ml] = Ys[ml*16+t][o]
    #pragma unroll
    for (int it = 0; it < 4; ++it) {
        int r = it * 256 + tid;
        int o = r >> 4, t = r & 15;
        u16x8 v0, v1;
        #pragma unroll
        for (int q = 0; q < 8; ++q) {
            v0[q] = Ys[(q * 16 + t) * 72 + o];
            v1[q] = Ys[((q + 8) * 16 + t) * 72 + o];
        }
        unsigned short* dst = Yt + (((size_t)b << 10) + r) * 1024 + m0;
        *(u16x8*)dst = v0;
        *(u16x8*)(dst + 8) = v1;
    }
}

// ---------------- kBP: P panel ----------------
__global__ __launch_bounds__(256) void kBP(const float* __restrict__ kk_,
                                           const float* __restrict__ kq_,
                                           const float* __restrict__ adj,
                                           unsigned short* __restrict__ Pbf) {
    int tid = threadIdx.x;
    int b  = blockIdx.x >> 8;
    int n0 = (blockIdx.x & 255) * 4;
    __shared__ float kql[4][16];
    __shared__ float redm[4][4], reds[4][4];
    if (tid < 64)
        kql[tid >> 4][tid & 15] =
            kq_[((size_t)b * 1024 + n0 + (tid >> 4)) * 16 + (tid & 15)];
    __syncthreads();
    const float* kb = kk_ + (size_t)b * 16384;
    float kf[4][16];
    #pragma unroll
    for (int u = 0; u < 4; ++u) {
        const float* p = &kb[(size_t)(u * 256 + tid) * 16];
        #pragma unroll
        for (int s = 0; s < 16; ++s) kf[u][s] = p[s];
    }
    float sc[4][4];
    #pragma unroll
    for (int r = 0; r < 4; ++r)
        #pragma unroll
        for (int u = 0; u < 4; ++u) {
            float a = 0.f;
            #pragma unroll
            for (int s = 0; s < 16; ++s) a = fmaf(kql[r][s], kf[u][s], a);
            sc[r][u] = a;
        }
    float mx[4];
    #pragma unroll
    for (int r = 0; r < 4; ++r)
        mx[r] = fmaxf(fmaxf(sc[r][0], sc[r][1]), fmaxf(sc[r][2], sc[r][3]));
    #pragma unroll
    for (int off = 32; off; off >>= 1)
        #pragma unroll
        for (int r = 0; r < 4; ++r) mx[r] = fmaxf(mx[r], __shfl_xor(mx[r], off));
    int w = tid >> 6;
    if ((tid & 63) == 0)
        #pragma unroll
        for (int r = 0; r < 4; ++r) redm[w][r] = mx[r];
    __syncthreads();
    #pragma unroll
    for (int r = 0; r < 4; ++r)
        mx[r] = fmaxf(fmaxf(redm[0][r], redm[1][r]), fmaxf(redm[2][r], redm[3][r]));
    float e[4][4], se[4];
    #pragma unroll
    for (int r = 0; r < 4; ++r) {
        float s = 0.f;
        #pragma unroll
        for (int u = 0; u < 4; ++u) { e[r][u] = __expf(sc[r][u] - mx[r]); s += e[r][u]; }
        se[r] = s;
    }
    #pragma unroll
    for (int off = 32; off; off >>= 1)
        #pragma unroll
        for (int r = 0; r < 4; ++r) se[r] += __shfl_xor(se[r], off);
    if ((tid & 63) == 0)
        #pragma unroll
        for (int r = 0; r < 4; ++r) reds[w][r] = se[r];
    __syncthreads();
    float rrs[4];
    #pragma unroll
    for (int r = 0; r < 4; ++r)
        rrs[r] = 1.f / (reds[0][r] + reds[1][r] + reds[2][r] + reds[3][r]);
    #pragma unroll
    for (int r = 0; r < 4; ++r)
        #pragma unroll
        for (int u = 0; u < 4; ++u) {
            size_t m = (size_t)u * 256 + tid;
            float av = adj[(size_t)(n0 + r) * 1024 + m];
            Pbf[((size_t)b * 1024 + n0 + r) * 1024 + m] = f2bf(e[r][u] * rrs[r] * av);
        }
}

// ---------------- kD: main GEMM ----------------
// stage one 256x32 K-tile of A(P) and B(Yt). Source chunk pre-swizzled by
// S(row) = (row ^ (row>>2)) & 3; LDS dest linear (rule #21).
static __device__ __forceinline__ void stage32(const unsigned short* Pb,
                                               const unsigned short* Yb,
                                               unsigned short* lds, int buf,
                                               int kt, int ww, int l) {
    int S  = ((l >> 2) ^ (l >> 4)) & 3;
    int cs = (((l & 3) ^ S)) << 3;       // source chunk (ushorts)
    int k0 = kt << 5;
    unsigned short* base = lds + buf * 16384;
    #pragma unroll
    for (int s = 0; s < 2; ++s) {
        int rbase = s * 128 + ww * 16;                      // wave-uniform
        size_t g = ((size_t)(rbase + (l >> 2)) << 10) + k0 + cs;
        GLOAD_LDS16(Pb + g, base + rbase * 32);
        GLOAD_LDS16(Yb + g, base + 8192 + rbase * 32);
    }
}

static __device__ __forceinline__ s16x8 frag32(const unsigned short* base,
                                               int row, int l) {
    int S = (row ^ (row >> 2)) & 3;
    int g = (l >> 4) & 3;
    return *(const s16x8*)(base + row * 32 + ((g ^ S) << 3));
}

__global__ __launch_bounds__(512, 2) void kD(const unsigned short* __restrict__ P,
                                             const unsigned short* __restrict__ Yt,
                                             float* __restrict__ out) {
    extern __shared__ unsigned short lds[];   // 3 bufs x 32 KB = 96 KiB
    int bid = blockIdx.x;
    int wg  = (bid & 7) * 64 + (bid >> 3);    // XCD-grouped (512 % 8 == 0)
    int b   = wg >> 4;
    int rem = wg & 15;
    int n0  = (rem & 3) << 8;
    int j0  = (rem >> 2) << 8;
    int tid = threadIdx.x;
    int l = tid & 63, ww = tid >> 6;
    int wr = ww >> 2, wc = ww & 3;
    int l15 = l & 15, lhi = l >> 4;
    const unsigned short* Pb = P  + ((size_t)b << 20) + ((size_t)n0 << 10);
    const unsigned short* Yb = Yt + ((size_t)b << 20) + ((size_t)j0 << 10);

    f32x4 acc[8][4] = {};
    stage32(Pb, Yb, lds, 0, 0, ww, l);
    stage32(Pb, Yb, lds, 1, 1, ww, l);

    for (int kt = 0; kt < 32; ++kt) {
        int cur = kt % 3;
        const unsigned short* Ab = lds + cur * 16384;
        const unsigned short* Bb = Ab + 8192;
        if (kt < 31) asm volatile("s_waitcnt vmcnt(4)" ::: "memory");
        else         asm volatile("s_waitcnt vmcnt(0)" ::: "memory");
        __builtin_amdgcn_s_barrier();
        // phase 0: B frags + A frags 0..3, stage kt+2
        s16x8 bf[4], af0[4];
        #pragma unroll
        for (int nj = 0; nj < 4; ++nj)
            bf[nj] = frag32(Bb, wc * 64 + nj * 16 + l15, l);
        #pragma unroll
        for (int mi = 0; mi < 4; ++mi)
            af0[mi] = frag32(Ab, wr * 128 + mi * 16 + l15, l);
        if (kt < 30) stage32(Pb, Yb, lds, (kt + 2) % 3, kt + 2, ww, l);
        __builtin_amdgcn_s_barrier();
        asm volatile("s_waitcnt lgkmcnt(0)" ::: "memory");
        __builtin_amdgcn_sched_barrier(0);
        __builtin_amdgcn_s_setprio(1);
        #pragma unroll
        for (int mi = 0; mi < 4; ++mi)
            #pragma unroll
            for (int nj = 0; nj < 4; ++nj)
                acc[mi][nj] = __builtin_amdgcn_mfma_f32_16x16x32_bf16(
                    af0[mi], bf[nj], acc[mi][nj], 0, 0, 0);
        __builtin_amdgcn_s_setprio(0);
        __builtin_amdgcn_s_barrier();
        // phase 1: A frags 4..7 (reuse B frags)
        s16x8 af1[4];
        #pragma unroll
        for (int mi = 0; mi < 4; ++mi)
            af1[mi] = frag32(Ab, wr * 128 + (4 + mi) * 16 + l15, l);
        asm volatile("s_waitcnt lgkmcnt(0)" ::: "memory");
        __builtin_amdgcn_sched_barrier(0);
        __builtin_amdgcn_s_setprio(1);
        #pragma unroll
        for (int mi = 0; mi < 4; ++mi)
            #pragma unroll
            for (int nj = 0; nj < 4; ++nj)
                acc[4 + mi][nj] = __builtin_amdgcn_mfma_f32_16x16x32_bf16(
                    af1[mi], bf[nj], acc[4 + mi][nj], 0, 0, 0);
        __builtin_amdgcn_s_setprio(0);
    }

    #pragma unroll
    for (int mi = 0; mi < 8; ++mi)
        #pragma unroll
        for (int nj = 0; nj < 4; ++nj) {
            int o  = (j0 >> 4) + wc * 4 + nj;
            int nb = n0 + wr * 128 + mi * 16 + lhi * 4;
            float* op = out + ((size_t)(b * 64 + o) << 14) + (size_t)nb * 16 + l15;
            #pragma unroll
            for (int q = 0; q < 4; ++q) op[q * 16] = acc[mi][nj][q];
        }
}

extern "C" void kernel_launch(void* const* d_in, const int* in_sizes, int n_in,
                              void* d_out, int out_size, void* d_ws, size_t ws_size,
                              hipStream_t stream) {
    const float* x     = (const float*)d_in[0];
    const float* adj   = (const float*)d_in[1];
    const float* alpha = (const float*)d_in[2];
    const float* Watt  = (const float*)d_in[3];
    const float* Wout  = (const float*)d_in[4];
    float* out = (float*)d_out;

    char* ws = (char*)d_ws;
    float* k  = (float*)ws;                                            // 2 MB
    float* kq = (float*)(ws + 2097152);                                // 2 MB
    unsigned short* Pbf = (unsigned short*)(ws + 4194304);             // 64 MB
    unsigned short* Yt  = (unsigned short*)(ws + 4194304 + 67108864);  // 64 MB

    kCM<<<2048, 256, 78144, stream>>>(x, Wout, alpha, Watt, Yt, k, kq);
    kBP<<<8192, 256, 0, stream>>>(k, kq, adj, Pbf);
    kD <<<512, 512, 98304, stream>>>(Pbf, Yt, out);
}

// Round 6
// 193.811 us; speedup vs baseline: 23.3066x; 1.0422x over previous
//
#include <hip/hip_runtime.h>
#include <hip/hip_bf16.h>

// B=32, C_IN=64, C_OUT=64, N=1024, T=16
//  kCM: fused kA+kC+kT — MFMA y=W_out@x (bf16) -> Yt[b][j=o*16+t][m];
//       k computed in fp32 DURING global staging (no serial chain); kq fp32.
//       52.5 KB LDS -> 3 blocks/CU.
//  kBP: Pbf[b][n][m] = bf16( softmax_m(kq[n]·k[m]) * adj )
//  kD : out = P@Yt — 256x256, BK=64, 4-phase, src-swizzled linear LDS,
//       global_load_lds(16B), T5 setprio, XCD-grouped (round-4 proven).

typedef float  f32x4 __attribute__((ext_vector_type(4)));
typedef short  s16x8 __attribute__((ext_vector_type(8)));
typedef unsigned short u16x8 __attribute__((ext_vector_type(8)));

#define GLOAD_LDS16(g, l) __builtin_amdgcn_global_load_lds(                    \
    (const __attribute__((address_space(1))) void*)(g),                        \
    (__attribute__((address_space(3))) void*)(l), 16, 0, 0)

static __device__ __forceinline__ unsigned short f2bf(float f) {
    __hip_bfloat16 h = __float2bfloat16(f);
    return *reinterpret_cast<unsigned short*>(&h);
}

// ---------------- kCM2: fused y-GEMM + transpose + k/kq ----------------
// block = (b, 16 m = 256 j), 256 threads.
// LDS map: [0,36864) = xtb u16[64][264] (33792) overlapped by Ys u16[256][72];
// Wb u16[64][72] @36864; al @46080; wl[16][17] @46336; kl[256] @47424;
// kred[4][256] @48448; total 52544.
__global__ __launch_bounds__(256, 3) void kCM(const float* __restrict__ x,
                                              const float* __restrict__ Wout,
                                              const float* __restrict__ alpha,
                                              const float* __restrict__ Watt,
                                              unsigned short* __restrict__ Yt,
                                              float* __restrict__ kk_,
                                              float* __restrict__ kq_) {
    extern __shared__ char sm[];
    unsigned short* xtb = (unsigned short*)sm;            // [64][264]
    unsigned short* Ys  = (unsigned short*)sm;            // [256][72] (xtb dead)
    unsigned short* Wb  = (unsigned short*)(sm + 36864);  // [64][72]
    float* al   = (float*)(sm + 46080);
    float* wl   = (float*)(sm + 46336);                   // [16][17]
    float* kl   = (float*)(sm + 47424);                   // [256]
    float* kred = (float*)(sm + 48448);                   // [4][256]
    int tid = threadIdx.x;
    int b  = blockIdx.x >> 6;
    int mc = blockIdx.x & 63;
    int j0 = mc << 8;
    int m0 = mc << 4;
    int g = tid >> 6, lane = tid & 63;
    if (tid < 64) al[tid] = alpha[tid];
    wl[(tid >> 4) * 17 + (tid & 15)] = Watt[tid];
    #pragma unroll
    for (int it = 0; it < 16; ++it) {
        int idx = it * 256 + tid;
        Wb[(idx >> 6) * 72 + (idx & 63)] = f2bf(Wout[idx]);
    }
    __syncthreads();
    // stage x (bf16) + fp32 k-partials on the fly
    const float* xb = x + (size_t)b * (64 * 16384) + j0;
    float kp[4] = {0.f, 0.f, 0.f, 0.f};
    #pragma unroll
    for (int it = 0; it < 16; ++it) {
        int c = it * 4 + g;                       // wave-uniform
        float4 v = *(const float4*)(xb + (size_t)c * 16384 + lane * 4);
        float a = al[c];
        kp[0] = fmaf(a, v.x, kp[0]);
        kp[1] = fmaf(a, v.y, kp[1]);
        kp[2] = fmaf(a, v.z, kp[2]);
        kp[3] = fmaf(a, v.w, kp[3]);
        ushort4 pk = make_ushort4(f2bf(v.x), f2bf(v.y), f2bf(v.z), f2bf(v.w));
        *(ushort4*)&xtb[c * 264 + lane * 4] = pk;
    }
    *(float4*)&kred[g * 256 + lane * 4] = make_float4(kp[0], kp[1], kp[2], kp[3]);
    __syncthreads();
    // frags -> regs; k reduce
    int l15 = lane & 15, lhi = lane >> 4;
    int jw = g << 6;
    s16x8 af[4][2], bfv[4][2];
    #pragma unroll
    for (int fro = 0; fro < 4; ++fro)
        #pragma unroll
        for (int ks = 0; ks < 2; ++ks)
            af[fro][ks] = *(const s16x8*)&Wb[(fro * 16 + l15) * 72 + ks * 32 + lhi * 8];
    #pragma unroll
    for (int fc = 0; fc < 4; ++fc)
        #pragma unroll
        for (int ks = 0; ks < 2; ++ks) {
            int jcol = jw + fc * 16 + l15;
            int cb = ks * 32 + lhi * 8;
            s16x8 t;
            #pragma unroll
            for (int e = 0; e < 8; ++e)
                t[e] = (short)xtb[(cb + e) * 264 + jcol];
            bfv[fc][ks] = t;
        }
    float kv = kred[tid] + kred[256 + tid] + kred[512 + tid] + kred[768 + tid];
    kl[tid] = kv;
    kk_[(size_t)b * 16384 + j0 + tid] = kv;
    __syncthreads();   // xtb dead; kl ready
    // MFMA y = W @ x
    f32x4 acc[4][4] = {};
    #pragma unroll
    for (int ks = 0; ks < 2; ++ks)
        #pragma unroll
        for (int fc = 0; fc < 4; ++fc)
            #pragma unroll
            for (int fro = 0; fro < 4; ++fro)
                acc[fro][fc] = __builtin_amdgcn_mfma_f32_16x16x32_bf16(
                    af[fro][ks], bfv[fc][ks], acc[fro][fc], 0, 0, 0);
    // kq
    {
        int ml = tid >> 4, tq = tid & 15;
        float q = 0.f;
        #pragma unroll
        for (int s = 0; s < 16; ++s) q = fmaf(kl[ml * 16 + s], wl[s * 17 + tq], q);
        kq_[(size_t)b * 16384 + j0 + tid] = q;
    }
    // C frags -> Ys[j_local][o]
    #pragma unroll
    for (int fro = 0; fro < 4; ++fro)
        #pragma unroll
        for (int fc = 0; fc < 4; ++fc) {
            int jl = jw + fc * 16 + l15;
            int o0 = fro * 16 + lhi * 4;
            ushort4 pk = make_ushort4(f2bf(acc[fro][fc][0]), f2bf(acc[fro][fc][1]),
                                      f2bf(acc[fro][fc][2]), f2bf(acc[fro][fc][3]));
            *(ushort4*)&Ys[jl * 72 + o0] = pk;
        }
    __syncthreads();
    // Yt[b][r=o*16+t][m0+ml] = Ys[ml*16+t][o]
    #pragma unroll
    for (int it = 0; it < 4; ++it) {
        int r = it * 256 + tid;
        int o = r >> 4, t = r & 15;
        u16x8 v0, v1;
        #pragma unroll
        for (int q = 0; q < 8; ++q) {
            v0[q] = Ys[(q * 16 + t) * 72 + o];
            v1[q] = Ys[((q + 8) * 16 + t) * 72 + o];
        }
        unsigned short* dst = Yt + (((size_t)b << 10) + r) * 1024 + m0;
        *(u16x8*)dst = v0;
        *(u16x8*)(dst + 8) = v1;
    }
}

// ---------------- kBP: P panel ----------------
__global__ __launch_bounds__(256) void kBP(const float* __restrict__ kk_,
                                           const float* __restrict__ kq_,
                                           const float* __restrict__ adj,
                                           unsigned short* __restrict__ Pbf) {
    int tid = threadIdx.x;
    int b  = blockIdx.x >> 8;
    int n0 = (blockIdx.x & 255) * 4;
    __shared__ float kql[4][16];
    __shared__ float redm[4][4], reds[4][4];
    if (tid < 64)
        kql[tid >> 4][tid & 15] =
            kq_[((size_t)b * 1024 + n0 + (tid >> 4)) * 16 + (tid & 15)];
    __syncthreads();
    const float* kb = kk_ + (size_t)b * 16384;
    float kf[4][16];
    #pragma unroll
    for (int u = 0; u < 4; ++u) {
        const float* p = &kb[(size_t)(u * 256 + tid) * 16];
        #pragma unroll
        for (int s = 0; s < 16; ++s) kf[u][s] = p[s];
    }
    float sc[4][4];
    #pragma unroll
    for (int r = 0; r < 4; ++r)
        #pragma unroll
        for (int u = 0; u < 4; ++u) {
            float a = 0.f;
            #pragma unroll
            for (int s = 0; s < 16; ++s) a = fmaf(kql[r][s], kf[u][s], a);
            sc[r][u] = a;
        }
    float mx[4];
    #pragma unroll
    for (int r = 0; r < 4; ++r)
        mx[r] = fmaxf(fmaxf(sc[r][0], sc[r][1]), fmaxf(sc[r][2], sc[r][3]));
    #pragma unroll
    for (int off = 32; off; off >>= 1)
        #pragma unroll
        for (int r = 0; r < 4; ++r) mx[r] = fmaxf(mx[r], __shfl_xor(mx[r], off));
    int w = tid >> 6;
    if ((tid & 63) == 0)
        #pragma unroll
        for (int r = 0; r < 4; ++r) redm[w][r] = mx[r];
    __syncthreads();
    #pragma unroll
    for (int r = 0; r < 4; ++r)
        mx[r] = fmaxf(fmaxf(redm[0][r], redm[1][r]), fmaxf(redm[2][r], redm[3][r]));
    float e[4][4], se[4];
    #pragma unroll
    for (int r = 0; r < 4; ++r) {
        float s = 0.f;
        #pragma unroll
        for (int u = 0; u < 4; ++u) { e[r][u] = __expf(sc[r][u] - mx[r]); s += e[r][u]; }
        se[r] = s;
    }
    #pragma unroll
    for (int off = 32; off; off >>= 1)
        #pragma unroll
        for (int r = 0; r < 4; ++r) se[r] += __shfl_xor(se[r], off);
    if ((tid & 63) == 0)
        #pragma unroll
        for (int r = 0; r < 4; ++r) reds[w][r] = se[r];
    __syncthreads();
    float rrs[4];
    #pragma unroll
    for (int r = 0; r < 4; ++r)
        rrs[r] = 1.f / (reds[0][r] + reds[1][r] + reds[2][r] + reds[3][r]);
    #pragma unroll
    for (int r = 0; r < 4; ++r)
        #pragma unroll
        for (int u = 0; u < 4; ++u) {
            size_t m = (size_t)u * 256 + tid;
            float av = adj[(size_t)(n0 + r) * 1024 + m];
            Pbf[((size_t)b * 1024 + n0 + r) * 1024 + m] = f2bf(e[r][u] * rrs[r] * av);
        }
}

// ---------------- kD: main GEMM (round-4 proven structure) ----------------
static __device__ __forceinline__ void stage_tile(const unsigned short* Pb,
                                                  const unsigned short* Yb,
                                                  unsigned short* lds, int buf,
                                                  int kt, int ww, int l) {
    int r8  = (l >> 3) & 7;
    int glc = ((l & 7) ^ r8) << 3;       // swizzled source k-offset (ushorts)
    int k0  = kt << 6;
    unsigned short* base = lds + buf * 32768;
    #pragma unroll
    for (int s = 0; s < 4; ++s) {
        int row  = s * 64 + ww * 8;                       // wave-uniform
        size_t g = ((size_t)(row + r8) << 10) + k0 + glc; // per-lane
        GLOAD_LDS16(Pb + g, base + row * 64);
        GLOAD_LDS16(Yb + g, base + 16384 + row * 64);
    }
}

static __device__ __forceinline__ s16x8 frag_ld(const unsigned short* base,
                                                int R, int kc, int l7) {
    return *(const s16x8*)(base + R * 64 + ((kc ^ l7) << 3));
}

__global__ __launch_bounds__(512, 2) void kD(const unsigned short* __restrict__ P,
                                             const unsigned short* __restrict__ Yt,
                                             float* __restrict__ out) {
    extern __shared__ unsigned short lds[];   // 2 * (256*64 A + 256*64 B) = 128 KiB
    int bid = blockIdx.x;
    int wg  = (bid & 7) * 64 + (bid >> 3);    // XCD-grouped (512 % 8 == 0)
    int b   = wg >> 4;
    int rem = wg & 15;
    int n0  = (rem & 3) << 8;
    int j0  = (rem >> 2) << 8;
    int tid = threadIdx.x;
    int l = tid & 63, ww = tid >> 6;
    int wr = ww >> 2, wc = ww & 3;       // 2 x 4 wave grid
    int l15 = l & 15, lhi = l >> 4, l7 = l & 7;
    const unsigned short* Pb = P  + ((size_t)b << 20) + ((size_t)n0 << 10);
    const unsigned short* Yb = Yt + ((size_t)b << 20) + ((size_t)j0 << 10);

    f32x4 acc[8][4] = {};
    stage_tile(Pb, Yb, lds, 0, 0, ww, l);
    __syncthreads();

    for (int kt = 0; kt < 16; ++kt) {
        int cur = kt & 1;
        const unsigned short* Ab = lds + cur * 32768;
        const unsigned short* Bb = Ab + 16384;
        s16x8 bf[4][2];
        #pragma unroll
        for (int q = 0; q < 4; ++q) {
            if (q == 0) {
                int ktn = kt < 15 ? kt + 1 : 15;
                stage_tile(Pb, Yb, lds, cur ^ 1, ktn, ww, l);
                #pragma unroll
                for (int nj = 0; nj < 4; ++nj)
                    #pragma unroll
                    for (int ks = 0; ks < 2; ++ks)
                        bf[nj][ks] = frag_ld(Bb, wc * 64 + nj * 16 + l15,
                                             ks * 4 + lhi, l7);
            }
            s16x8 af[2][2];
            #pragma unroll
            for (int mi = 0; mi < 2; ++mi)
                #pragma unroll
                for (int ks = 0; ks < 2; ++ks)
                    af[mi][ks] = frag_ld(Ab, wr * 128 + (q * 2 + mi) * 16 + l15,
                                         ks * 4 + lhi, l7);
            __builtin_amdgcn_s_barrier();
            asm volatile("s_waitcnt lgkmcnt(0)" ::: "memory");
            __builtin_amdgcn_sched_barrier(0);
            __builtin_amdgcn_s_setprio(1);
            #pragma unroll
            for (int mi = 0; mi < 2; ++mi)
                #pragma unroll
                for (int nj = 0; nj < 4; ++nj)
                    #pragma unroll
                    for (int ks = 0; ks < 2; ++ks)
                        acc[q * 2 + mi][nj] = __builtin_amdgcn_mfma_f32_16x16x32_bf16(
                            af[mi][ks], bf[nj][ks], acc[q * 2 + mi][nj], 0, 0, 0);
            __builtin_amdgcn_s_setprio(0);
            if (q < 3) __builtin_amdgcn_s_barrier();
        }
        __syncthreads();   // tile end: drain (prefetch landed) + barrier
    }

    #pragma unroll
    for (int mi = 0; mi < 8; ++mi)
        #pragma unroll
        for (int nj = 0; nj < 4; ++nj) {
            int o  = (j0 >> 4) + wc * 4 + nj;
            int nb = n0 + wr * 128 + mi * 16 + lhi * 4;
            float* op = out + ((size_t)(b * 64 + o) << 14) + (size_t)nb * 16 + l15;
            #pragma unroll
            for (int q = 0; q < 4; ++q) op[q * 16] = acc[mi][nj][q];
        }
}

extern "C" void kernel_launch(void* const* d_in, const int* in_sizes, int n_in,
                              void* d_out, int out_size, void* d_ws, size_t ws_size,
                              hipStream_t stream) {
    const float* x     = (const float*)d_in[0];
    const float* adj   = (const float*)d_in[1];
    const float* alpha = (const float*)d_in[2];
    const float* Watt  = (const float*)d_in[3];
    const float* Wout  = (const float*)d_in[4];
    float* out = (float*)d_out;

    char* ws = (char*)d_ws;
    float* k  = (float*)ws;                                            // 2 MB
    float* kq = (float*)(ws + 2097152);                                // 2 MB
    unsigned short* Pbf = (unsigned short*)(ws + 4194304);             // 64 MB
    unsigned short* Yt  = (unsigned short*)(ws + 4194304 + 67108864);  // 64 MB

    kCM<<<2048, 256, 52544, stream>>>(x, Wout, alpha, Watt, Yt, k, kq);
    kBP<<<8192, 256, 0, stream>>>(k, kq, adj, Pbf);
    kD <<<512, 512, 131072, stream>>>(Pbf, Yt, out);
}